// Round 8
// baseline (115.413 us; speedup 1.0000x reference)
//
#include <hip/hip_runtime.h>
#include <cmath>

// SSIM + L1 image similarity loss, MI355X (gfx950).
// es, ta: fp32 [16,3,512,512]. Output: out[0]=l1_loss, out[1]=ssim_loss.
//
// R8: R7 hit 114.6us but VGPR=64 + WRITE_SIZE=84.6MB revealed the register
// allocator spilled ~20 dwords/thread to scratch chasing 8 waves/SIMD --
// pointless, since LDS (35.3KB -> 4 blocks/CU) caps the CU at 16 waves
// anyway. launch_bounds' 2nd arg is only a MINIMUM waves/EU; the allocator
// overshot. Fix: amdgpu_waves_per_eu(4,4) pins the target at exactly the
// LDS cap -> VGPR budget 128 >= live set (~80) -> no spill, same occupancy.
// Everything else identical to R7.

constexpr int TILE_W = 64;
constexpr int TILE_H = 48;
constexpr int HALO = 5;
constexpr int WIN  = 11;
constexpr int ROWS_PER_WAVE = TILE_H / 4;          // 12
constexpr int STREAM_ROWS = ROWS_PER_WAVE + WIN - 1; // 22
constexpr int LH   = TILE_H + 2 * HALO;  // 58 staged rows
constexpr int LW   = TILE_W + 2 * HALO;  // 74 staged cols
constexpr int LSTR = 76;                 // LDS row stride (float2 units)
constexpr int IMG  = 512;
constexpr float C1C = 0.01f * 0.01f;
constexpr float C2C = 0.03f * 0.03f;

struct Wnd { float g[WIN]; };

__global__ __launch_bounds__(256)
__attribute__((amdgpu_waves_per_eu(4, 4)))
void ssim_main(
    const float* __restrict__ es, const float* __restrict__ ta,
    float2* __restrict__ partials, Wnd w)
{
    __shared__ float2 sS[LH * LSTR];
    __shared__ float2 red[4];

    const int tid = threadIdx.x;
    const int tx0 = blockIdx.x * TILE_W;
    const int ty0 = blockIdx.y * TILE_H;
    const int img = blockIdx.z;
    const float* pe = es + (size_t)img * (IMG * IMG);
    const float* pt = ta + (size_t)img * (IMG * IMG);

    // ---- stage interleaved {e,t} tile (zero-pad outside image) ----
    for (int i = tid; i < LH * LW; i += 256) {
        int r = i / LW;
        int c = i - r * LW;
        int gy = ty0 - HALO + r;
        int gx = tx0 - HALO + c;
        float ev = 0.f, tv = 0.f;
        if (gy >= 0 && gy < IMG && gx >= 0 && gx < IMG) {
            int off = gy * IMG + gx;
            ev = pe[off];
            tv = pt[off];
        }
        sS[r * LSTR + c] = make_float2(ev, tv);
    }
    __syncthreads();

    const int wv = tid >> 6;   // wave id 0..3 -> 12-row segment
    const int ln = tid & 63;   // lane -> column
    const int rbase = wv * ROWS_PER_WAVE;
    const float2* rp = &sS[rbase * LSTR + ln];

    float hw[5][WIN];          // circular window of horizontal sums
    float ssim_s = 0.f, l1_s = 0.f;

    #pragma unroll
    for (int rr = 0; rr < STREAM_ROWS; ++rr) {
        // horizontal 11-tap of {e, t, e^2, t^2, e*t} for streamed row rr
        float hm1 = 0.f, hm2 = 0.f, h11 = 0.f, h22 = 0.f, h12 = 0.f;
        #pragma unroll
        for (int k = 0; k < WIN; ++k) {
            float2 v = rp[rr * LSTR + k];   // ds_read_b64, imm offset
            float gk = w.g[k];
            float ge = gk * v.x;
            float gt = gk * v.y;
            hm1 += ge;
            hm2 += gt;
            h11 += ge * v.x;
            h22 += gt * v.y;
            h12 += ge * v.y;
        }
        const int s = rr % WIN;            // constant after unroll
        hw[0][s] = hm1; hw[1][s] = hm2; hw[2][s] = h11;
        hw[3][s] = h22; hw[4][s] = h12;

        if (rr >= WIN - 1) {
            const int o = rr - (WIN - 1);  // completed output row
            float mu1 = 0.f, mu2 = 0.f, x11 = 0.f, x22 = 0.f, x12 = 0.f;
            #pragma unroll
            for (int k = 0; k < WIN; ++k) {
                const int idx = (o + k) % WIN;  // constant after unroll
                float gk = w.g[k];
                mu1 += gk * hw[0][idx];
                mu2 += gk * hw[1][idx];
                x11 += gk * hw[2][idx];
                x22 += gk * hw[3][idx];
                x12 += gk * hw[4][idx];
            }
            if (ty0 + rbase + o < IMG) {   // skip padded rows (last stripe)
                float m11 = mu1 * mu1, m22 = mu2 * mu2, m12 = mu1 * mu2;
                float s11 = x11 - m11;
                float s22 = x22 - m22;
                float s12 = x12 - m12;
                float num = (2.f * m12 + C1C) * (2.f * s12 + C2C);
                float den = (m11 + m22 + C1C) * (s11 + s22 + C2C);
                ssim_s += num * __builtin_amdgcn_rcpf(den);

                float2 c = rp[(o + HALO) * LSTR + HALO];  // center {e,t}
                l1_s += fabsf(c.x - c.y);
            }
        }
    }

    // ---- block reduce: wave shfl -> LDS[4] -> thread 0 stores partial ----
    #pragma unroll
    for (int off = 32; off >= 1; off >>= 1) {
        ssim_s += __shfl_xor(ssim_s, off, 64);
        l1_s   += __shfl_xor(l1_s, off, 64);
    }
    if (ln == 0) red[wv] = make_float2(ssim_s, l1_s);
    __syncthreads();
    if (tid == 0) {
        float2 r0 = red[0], r1 = red[1], r2 = red[2], r3 = red[3];
        float2 p = make_float2(r0.x + r1.x + r2.x + r3.x,
                               r0.y + r1.y + r2.y + r3.y);
        int bid = (blockIdx.z * gridDim.y + blockIdx.y) * gridDim.x + blockIdx.x;
        partials[bid] = p;
    }
}

__global__ __launch_bounds__(256) void ssim_reduce(
    const float2* __restrict__ partials, int n, float* __restrict__ out)
{
    __shared__ float2 red[4];
    const int tid = threadIdx.x;
    float ssim_s = 0.f, l1_s = 0.f;
    for (int i = tid; i < n; i += 256) {
        float2 p = partials[i];
        ssim_s += p.x;
        l1_s   += p.y;
    }
    #pragma unroll
    for (int off = 32; off >= 1; off >>= 1) {
        ssim_s += __shfl_xor(ssim_s, off, 64);
        l1_s   += __shfl_xor(l1_s, off, 64);
    }
    if ((tid & 63) == 0) red[tid >> 6] = make_float2(ssim_s, l1_s);
    __syncthreads();
    if (tid == 0) {
        float s = red[0].x + red[1].x + red[2].x + red[3].x;
        float l = red[0].y + red[1].y + red[2].y + red[3].y;
        const float N = 16.f * 3.f * 512.f * 512.f;
        out[0] = 0.15f * (l / N);
        out[1] = 0.85f * 0.5f * (1.f - s / N);
    }
}

extern "C" void kernel_launch(void* const* d_in, const int* in_sizes, int n_in,
                              void* d_out, int out_size, void* d_ws, size_t ws_size,
                              hipStream_t stream)
{
    const float* es = (const float*)d_in[0];
    const float* ta = (const float*)d_in[1];
    float* out = (float*)d_out;
    float2* partials = (float2*)d_ws;

    Wnd w;
    double gd[WIN], sum = 0.0;
    for (int i = 0; i < WIN; ++i) {
        double x = (double)(i - WIN / 2);
        gd[i] = std::exp(-(x * x) / (2.0 * 1.5 * 1.5));
        sum += gd[i];
    }
    for (int i = 0; i < WIN; ++i) w.g[i] = (float)(gd[i] / sum);

    const int nimg = in_sizes[0] / (IMG * IMG);  // 16*3 = 48
    dim3 grid(IMG / TILE_W, (IMG + TILE_H - 1) / TILE_H, nimg);  // 8 x 11 x 48
    const int nblocks = grid.x * grid.y * grid.z;                // 4224
    ssim_main<<<grid, 256, 0, stream>>>(es, ta, partials, w);
    ssim_reduce<<<1, 256, 0, stream>>>(partials, nblocks, out);
}